// Round 5
// baseline (364.285 us; speedup 1.0000x reference)
//
#include <hip/hip_runtime.h>

#define BATCH 256
#define NNODE 512
#define RPW 16   // rows per wave

typedef float floatx4 __attribute__((ext_vector_type(4)));

__global__ void init_out_kernel(const float* __restrict__ b2, float* __restrict__ out) {
    int i = blockIdx.x * blockDim.x + threadIdx.x;
    if (i < BATCH) out[i] = (float)NNODE * b2[0];
}

// grid: BATCH*8 blocks, 256 threads (4 waves). Block (b,chunk) -> rows [chunk*64, +64).
// Wave streams 16 consecutive rows; lane l reads float4 cols c0=l and c1=l+64 ->
// every wave-load is ONE contiguous 1KB segment. x fragments are row-invariant
// registers. NEW vs R4: (1) no nontemporal flag; (2) butterfly+MLP folded into
// the per-row loop, so row r's DS-pipe reduction overlaps rows r+1.. VMEM loads
// (fine-grained vmcnt instead of a full drain before a serial tail), and live
// state is 2 scalars/row instead of 32 accumulators (lower VGPR -> occupancy).
__global__ __launch_bounds__(256, 4) void gcn_main_kernel(
    const float* __restrict__ x,    // [B,N,2]
    const float* __restrict__ adj,  // [B,N,N]
    const float* __restrict__ W1,   // [2,4]
    const float* __restrict__ b1,   // [4]
    const float* __restrict__ W2,   // [4,1]
    float* __restrict__ out)        // [B]
{
    __shared__ __align__(16) float sx0[NNODE];
    __shared__ __align__(16) float sx1[NNODE];
    __shared__ float swsum[4];

    const int b     = blockIdx.x >> 3;
    const int chunk = blockIdx.x & 7;
    const int t     = threadIdx.x;

    // Stage node features once: deinterleave [m][2] -> sx0[], sx1[]
    {
        const float4 v = ((const float4*)(x + (size_t)b * NNODE * 2))[t];
        const int m = 2 * t;
        sx0[m]     = v.x; sx1[m]     = v.y;
        sx0[m + 1] = v.z; sx1[m + 1] = v.w;
    }

    float w1[8], bb1[4], w2[4];
#pragma unroll
    for (int j = 0; j < 8; ++j) w1[j] = W1[j];
#pragma unroll
    for (int j = 0; j < 4; ++j) { bb1[j] = b1[j]; w2[j] = W2[j]; }

    __syncthreads();

    const int wave = t >> 6;
    const int lane = t & 63;

    // Row-invariant x fragments -> registers; LDS traffic done after this.
    const floatx4* sx0v = (const floatx4*)sx0;
    const floatx4* sx1v = (const floatx4*)sx1;
    const int c0 = lane, c1 = lane + 64;
    const floatx4 x0a = sx0v[c0], x1a = sx1v[c0];
    const floatx4 x0b = sx0v[c1], x1b = sx1v[c1];

    const int row0 = chunk * 64 + wave * RPW;
    const floatx4* __restrict__ arow =
        (const floatx4*)(adj + ((size_t)b * NNODE + row0) * NNODE);

    float acc = 0.0f;
#pragma unroll
    for (int r = 0; r < RPW; ++r) {
        const floatx4 a0 = arow[(size_t)r * (NNODE / 4) + c0];
        const floatx4 a1 = arow[(size_t)r * (NNODE / 4) + c1];
        float s0 = a0.x * x0a.x + a0.y * x0a.y + a0.z * x0a.z + a0.w * x0a.w
                 + a1.x * x0b.x + a1.y * x0b.y + a1.z * x0b.z + a1.w * x0b.w;
        float s1 = a0.x * x1a.x + a0.y * x1a.y + a0.z * x1a.z + a0.w * x1a.w
                 + a1.x * x1b.x + a1.y * x1b.y + a1.z * x1b.z + a1.w * x1b.w;

        // 64-lane butterfly for this row (DS pipe; overlaps later rows' loads)
#pragma unroll
        for (int m = 1; m < 64; m <<= 1) {
            s0 += __shfl_xor(s0, m, 64);
            s1 += __shfl_xor(s1, m, 64);
        }

        // Tiny MLP (uniform across lanes, pure VALU)
        float p = 0.0f;
#pragma unroll
        for (int j = 0; j < 4; ++j) {
            float h = fmaf(s0, w1[j], fmaf(s1, w1[4 + j], bb1[j]));
            h = fmaxf(h, 0.0f);
            p = fmaf(h, w2[j], p);
        }
        acc += p;
    }

    if (lane == 0) swsum[wave] = acc;
    __syncthreads();
    if (t == 0) {
        atomicAdd(out + b, swsum[0] + swsum[1] + swsum[2] + swsum[3]);
    }
}

extern "C" void kernel_launch(void* const* d_in, const int* in_sizes, int n_in,
                              void* d_out, int out_size, void* d_ws, size_t ws_size,
                              hipStream_t stream) {
    const float* x   = (const float*)d_in[0];
    const float* adj = (const float*)d_in[1];
    const float* W1  = (const float*)d_in[2];
    const float* b1  = (const float*)d_in[3];
    const float* W2  = (const float*)d_in[4];
    const float* b2  = (const float*)d_in[5];
    float* out = (float*)d_out;

    hipLaunchKernelGGL(init_out_kernel, dim3(1), dim3(256), 0, stream, b2, out);
    hipLaunchKernelGGL(gcn_main_kernel, dim3(BATCH * 8), dim3(256), 0, stream,
                       x, adj, W1, b1, W2, out);
}

// Round 6
// 343.485 us; speedup vs baseline: 1.0606x; 1.0606x over previous
//
#include <hip/hip_runtime.h>

#define BATCH 256
#define NNODE 512
#define RPW 16   // rows per wave

typedef float floatx4 __attribute__((ext_vector_type(4)));

// grid: BATCH*8 blocks, 256 threads (4 waves). Block (b,chunk) -> rows [chunk*64, +64).
// Wave streams 16 consecutive rows; lane l reads float4 cols c0=l and c1=l+64 ->
// every wave-load is ONE contiguous 1KB segment. x fragments are row-invariant
// registers; hot loop is pure global_load_dwordx4 + FMA (R4 structure: loads+FMA
// phase separated from the butterfly phase — R5's fusion regressed 21us).
// d_out is memset to 0 by the launcher; the chunk==0 block folds in the N*b2 term.
__global__ __launch_bounds__(256, 4) void gcn_main_kernel(
    const float* __restrict__ x,    // [B,N,2]
    const float* __restrict__ adj,  // [B,N,N]
    const float* __restrict__ W1,   // [2,4]
    const float* __restrict__ b1,   // [4]
    const float* __restrict__ W2,   // [4,1]
    const float* __restrict__ b2,   // [1]
    float* __restrict__ out)        // [B]
{
    __shared__ __align__(16) float sx0[NNODE];
    __shared__ __align__(16) float sx1[NNODE];
    __shared__ float swsum[4];

    const int b     = blockIdx.x >> 3;
    const int chunk = blockIdx.x & 7;
    const int t     = threadIdx.x;

    // Stage node features once: deinterleave [m][2] -> sx0[], sx1[]
    {
        const float4 v = ((const float4*)(x + (size_t)b * NNODE * 2))[t];
        const int m = 2 * t;
        sx0[m]     = v.x; sx1[m]     = v.y;
        sx0[m + 1] = v.z; sx1[m + 1] = v.w;
    }

    float w1[8], bb1[4], w2[4];
#pragma unroll
    for (int j = 0; j < 8; ++j) w1[j] = W1[j];
#pragma unroll
    for (int j = 0; j < 4; ++j) { bb1[j] = b1[j]; w2[j] = W2[j]; }

    __syncthreads();

    const int wave = t >> 6;
    const int lane = t & 63;

    // Row-invariant x fragments -> registers; LDS traffic done after this.
    const floatx4* sx0v = (const floatx4*)sx0;
    const floatx4* sx1v = (const floatx4*)sx1;
    const int c0 = lane, c1 = lane + 64;
    const floatx4 x0a = sx0v[c0], x1a = sx1v[c0];
    const floatx4 x0b = sx0v[c1], x1b = sx1v[c1];

    const int row0 = chunk * 64 + wave * RPW;
    const floatx4* __restrict__ arow =
        (const floatx4*)(adj + ((size_t)b * NNODE + row0) * NNODE);

    float s0[RPW], s1[RPW];
#pragma unroll
    for (int r = 0; r < RPW; ++r) {
        const floatx4 a0 = __builtin_nontemporal_load(&arow[(size_t)r * (NNODE / 4) + c0]);
        const floatx4 a1 = __builtin_nontemporal_load(&arow[(size_t)r * (NNODE / 4) + c1]);
        s0[r] = a0.x * x0a.x + a0.y * x0a.y + a0.z * x0a.z + a0.w * x0a.w
              + a1.x * x0b.x + a1.y * x0b.y + a1.z * x0b.z + a1.w * x0b.w;
        s1[r] = a0.x * x1a.x + a0.y * x1a.y + a0.z * x1a.z + a0.w * x1a.w
              + a1.x * x1b.x + a1.y * x1b.y + a1.z * x1b.z + a1.w * x1b.w;
    }

    // Butterfly-reduce each row over all 64 lanes (independent chains, ILP).
#pragma unroll
    for (int m = 1; m < 64; m <<= 1) {
#pragma unroll
        for (int r = 0; r < RPW; ++r) {
            s0[r] += __shfl_xor(s0[r], m, 64);
            s1[r] += __shfl_xor(s1[r], m, 64);
        }
    }

    // Tiny MLP per row (uniform across lanes after butterfly; no divergence).
    float acc = 0.0f;
#pragma unroll
    for (int r = 0; r < RPW; ++r) {
        float p = 0.0f;
#pragma unroll
        for (int j = 0; j < 4; ++j) {
            float h = fmaf(s0[r], w1[j], fmaf(s1[r], w1[4 + j], bb1[j]));
            h = fmaxf(h, 0.0f);
            p = fmaf(h, w2[j], p);
        }
        acc += p;
    }

    if (lane == 0) swsum[wave] = acc;
    __syncthreads();
    if (t == 0) {
        float v = swsum[0] + swsum[1] + swsum[2] + swsum[3];
        if (chunk == 0) v += (float)NNODE * b2[0];   // fold bias (out was memset to 0)
        atomicAdd(out + b, v);
    }
}

extern "C" void kernel_launch(void* const* d_in, const int* in_sizes, int n_in,
                              void* d_out, int out_size, void* d_ws, size_t ws_size,
                              hipStream_t stream) {
    const float* x   = (const float*)d_in[0];
    const float* adj = (const float*)d_in[1];
    const float* W1  = (const float*)d_in[2];
    const float* b1  = (const float*)d_in[3];
    const float* W2  = (const float*)d_in[4];
    const float* b2  = (const float*)d_in[5];
    float* out = (float*)d_out;

    hipMemsetAsync(out, 0, BATCH * sizeof(float), stream);
    hipLaunchKernelGGL(gcn_main_kernel, dim3(BATCH * 8), dim3(256), 0, stream,
                       x, adj, W1, b1, W2, b2, out);
}